// Round 1
// baseline (1002.150 us; speedup 1.0000x reference)
//
#include <hip/hip_runtime.h>
#include <hip/hip_bf16.h>
#include <math.h>

// Problem constants
#define BB 8
#define NN 2048
#define DD 1024
#define EE 8
#define HH 4096
#define CAP 320
#define NTOK (BB*NN)        // 16384
#define MBC (BB*CAP)        // 2560 rows per expert GEMM

typedef __bf16 bf16x8 __attribute__((ext_vector_type(8)));
typedef float f32x4 __attribute__((ext_vector_type(4)));
typedef unsigned u32x4 __attribute__((ext_vector_type(4)));
typedef unsigned short u16x4 __attribute__((ext_vector_type(4)));
typedef unsigned short u16;

__device__ __forceinline__ u16 f2bf(float f) {
    unsigned u = __builtin_bit_cast(unsigned, f);
    u += 0x7FFFu + ((u >> 16) & 1u);        // RNE
    return (u16)(u >> 16);
}

__device__ __forceinline__ void async_cp16(const void* g, void* l) {
    __builtin_amdgcn_global_load_lds((const __attribute__((address_space(1))) void*)g,
                                     (__attribute__((address_space(3))) void*)l,
                                     16, 0, 0);
}

// ---------------------------------------------------------------- zero stats
__global__ void MoE_zero_stats(float* stats) {
    if (threadIdx.x < 128) stats[threadIdx.x] = 0.0f;   // proxy[64] + cnt[64]
}

// ---------------------------------------------------------------- gating
// one wave per token; fp64 logit accumulation; writes per-token records + loss partials
__global__ __launch_bounds__(256) void MoE_gating(
    const float* __restrict__ x, const float* __restrict__ wg,
    const float* __restrict__ rp,
    int* __restrict__ i1o, int* __restrict__ i2o,
    float* __restrict__ g1o, float* __restrict__ g2o, int* __restrict__ keepo,
    float* __restrict__ proxy, float* __restrict__ cnt1)
{
    __shared__ float wgT[8*1024];
    __shared__ float sprox[8];
    __shared__ float scnt[8];
    int tid = threadIdx.x;
    {   // stage wg transposed: wgT[e][d]
        int d0 = tid*4;
        #pragma unroll
        for (int j = 0; j < 4; j++) {
            int d = d0 + j;
            f32x4 a = *(const f32x4*)(wg + d*8);
            f32x4 b = *(const f32x4*)(wg + d*8 + 4);
            wgT[0*1024+d]=a[0]; wgT[1*1024+d]=a[1]; wgT[2*1024+d]=a[2]; wgT[3*1024+d]=a[3];
            wgT[4*1024+d]=b[0]; wgT[5*1024+d]=b[1]; wgT[6*1024+d]=b[2]; wgT[7*1024+d]=b[3];
        }
    }
    if (tid < 8) { sprox[tid] = 0.0f; scnt[tid] = 0.0f; }
    __syncthreads();

    int wid = tid >> 6, lane = tid & 63;
    int tok = blockIdx.x*4 + wid;
    int b = tok >> 11;
    const float* xr = x + (size_t)tok * DD;

    double acc[8];
    #pragma unroll
    for (int e = 0; e < 8; e++) acc[e] = 0.0;
    for (int i = 0; i < 16; i++) {
        float xv = xr[i*64 + lane];
        #pragma unroll
        for (int e = 0; e < 8; e++)
            acc[e] += (double)xv * (double)wgT[e*1024 + i*64 + lane];
    }
    #pragma unroll
    for (int e = 0; e < 8; e++) {
        double v = acc[e];
        for (int off = 32; off; off >>= 1) v += __shfl_down(v, off, 64);
        acc[e] = v;
    }
    if (lane == 0) {
        float l[8];
        #pragma unroll
        for (int e = 0; e < 8; e++) l[e] = (float)acc[e];
        int i1 = 0;
        #pragma unroll
        for (int e = 1; e < 8; e++) if (l[e] > l[i1]) i1 = e;
        int i2 = (i1 == 0) ? 1 : 0;
        #pragma unroll
        for (int e = 0; e < 8; e++) if (e != i1 && l[e] > l[i2]) i2 = e;
        float mx = l[i1], p[8], s = 0.0f;
        #pragma unroll
        for (int e = 0; e < 8; e++) { p[e] = expf(l[e] - mx); s += p[e]; }
        float inv = 1.0f / s;
        #pragma unroll
        for (int e = 0; e < 8; e++) p[e] *= inv;
        float gate1 = p[i1], gate2 = p[i2];
        float denom = gate1 + gate2 + 1e-9f;
        float g1 = gate1 / denom, g2 = gate2 / denom;
        int keep = (rp[tok] < g2 / 0.2f) ? 1 : 0;
        i1o[tok] = i1; i2o[tok] = i2; g1o[tok] = g1; g2o[tok] = g2; keepo[tok] = keep;
        #pragma unroll
        for (int e = 0; e < 8; e++) atomicAdd(&sprox[e], p[e]);
        atomicAdd(&scnt[i1], 1.0f);
    }
    __syncthreads();
    if (tid < 8) {
        atomicAdd(&proxy[b*8 + tid], sprox[tid]);
        atomicAdd(&cnt1[b*8 + tid], scnt[tid]);
    }
}

// ---------------------------------------------------------------- scan (positions)
// one block per b; 256 threads x 8 tokens; packed 8x16-bit prefix sums
__global__ __launch_bounds__(256) void MoE_scan(
    const int* __restrict__ i1, const int* __restrict__ i2, const int* __restrict__ keep,
    const float* __restrict__ g1, const float* __restrict__ g2,
    int* __restrict__ p1o, int* __restrict__ p2o,
    float* __restrict__ g1f, float* __restrict__ g2f,
    int* __restrict__ slot_token)
{
    int b = blockIdx.x, t = threadIdx.x;
    __shared__ unsigned long long s0[256], s1[256];
    for (int s = t; s < EE*CAP; s += 256) {
        int e = s / CAP, c = s % CAP;
        slot_token[(e*BB + b)*CAP + c] = -1;
    }
    int base = b*NN + t*8;

    // ---- phase 1: mask1 ----
    int e1v[8];
    unsigned long long u0 = 0, u1 = 0;
    #pragma unroll
    for (int j = 0; j < 8; j++) {
        int e = i1[base + j]; e1v[j] = e;
        if (e < 4) u0 += 1ull << (e*16); else u1 += 1ull << ((e-4)*16);
    }
    s0[t] = u0; s1[t] = u1;
    __syncthreads();
    for (int off = 1; off < 256; off <<= 1) {
        unsigned long long a0 = 0, a1 = 0;
        if (t >= off) { a0 = s0[t-off]; a1 = s1[t-off]; }
        __syncthreads();
        s0[t] += a0; s1[t] += a1;
        __syncthreads();
    }
    unsigned long long t0 = s0[255], t1 = s1[255];
    unsigned long long x0 = s0[t] - u0, x1 = s1[t] - u1;
    int run[8], mc[8];
    #pragma unroll
    for (int e = 0; e < 8; e++) {
        run[e] = (int)((e < 4 ? (x0 >> (e*16)) : (x1 >> ((e-4)*16))) & 0xFFFF);
        int tot = (int)((e < 4 ? (t0 >> (e*16)) : (t1 >> ((e-4)*16))) & 0xFFFF);
        mc[e] = tot < CAP ? tot : CAP;
    }
    #pragma unroll
    for (int j = 0; j < 8; j++) {
        int e = e1v[j];
        int p = run[e]++;
        bool v = p < CAP;
        p1o[base + j] = p;
        g1f[base + j] = v ? g1[base + j] : 0.0f;
        if (v) slot_token[(e*BB + b)*CAP + p] = t*8 + j;
    }
    __syncthreads();

    // ---- phase 2: mask2 (offset by mask1_count) ----
    int e2v[8], kv[8];
    u0 = 0; u1 = 0;
    #pragma unroll
    for (int j = 0; j < 8; j++) {
        int e = i2[base + j]; e2v[j] = e;
        int k = keep[base + j]; kv[j] = k;
        if (k) { if (e < 4) u0 += 1ull << (e*16); else u1 += 1ull << ((e-4)*16); }
    }
    s0[t] = u0; s1[t] = u1;
    __syncthreads();
    for (int off = 1; off < 256; off <<= 1) {
        unsigned long long a0 = 0, a1 = 0;
        if (t >= off) { a0 = s0[t-off]; a1 = s1[t-off]; }
        __syncthreads();
        s0[t] += a0; s1[t] += a1;
        __syncthreads();
    }
    x0 = s0[t] - u0; x1 = s1[t] - u1;
    #pragma unroll
    for (int e = 0; e < 8; e++)
        run[e] = mc[e] + (int)((e < 4 ? (x0 >> (e*16)) : (x1 >> ((e-4)*16))) & 0xFFFF);
    #pragma unroll
    for (int j = 0; j < 8; j++) {
        if (kv[j]) {
            int e = e2v[j];
            int p = run[e]++;
            bool v = p < CAP;
            p2o[base + j] = p;
            g2f[base + j] = v ? g2[base + j] : 0.0f;
            if (v) slot_token[(e*BB + b)*CAP + p] = t*8 + j;
        } else {
            p2o[base + j] = 0;
            g2f[base + j] = 0.0f;
        }
    }
}

// ---------------------------------------------------------------- dispatch gather -> bf16
__global__ __launch_bounds__(256) void MoE_dispatch(
    const float* __restrict__ x, const int* __restrict__ slot_token,
    u16* __restrict__ Abuf)
{
    int tid = threadIdx.x, wid = tid >> 6, lane = tid & 63;
    int slot = blockIdx.x*4 + wid;            // (e*8+b)*320+c
    int b = (slot % (BB*CAP)) / CAP;
    int tok = slot_token[slot];
    u16* dst = Abuf + (size_t)slot * DD;
    if (tok >= 0) {
        const float* src = x + ((size_t)b*NN + tok) * DD;
        #pragma unroll
        for (int i = 0; i < 4; i++) {
            f32x4 v = *(const f32x4*)(src + (lane + 64*i)*4);
            u16x4 w = { f2bf(v[0]), f2bf(v[1]), f2bf(v[2]), f2bf(v[3]) };
            *(u16x4*)(dst + (lane + 64*i)*4) = w;
        }
    } else {
        u16x4 z = {0,0,0,0};
        #pragma unroll
        for (int i = 0; i < 4; i++) *(u16x4*)(dst + (lane + 64*i)*4) = z;
    }
}

// ---------------------------------------------------------------- weight transpose fp32[E][R][C] -> bf16[E][C][R]
__global__ __launch_bounds__(256) void MoE_transpose_bf16(
    const float* __restrict__ in, u16* __restrict__ out,
    int R, int C, int rTiles, int cTiles)
{
    int tilesPerE = rTiles * cTiles;
    int e = blockIdx.x / tilesPerE;
    int t = blockIdx.x % tilesPerE;
    int r0 = (t / cTiles) * 64, c0 = (t % cTiles) * 64;
    const float* ip = in + (size_t)e * R * C;
    u16* op = out + (size_t)e * R * C;
    __shared__ float T[64*65];
    int tid = threadIdx.x;
    int rr = tid >> 4, cx = tid & 15;
    #pragma unroll
    for (int i = 0; i < 4; i++) {
        int r = rr + i*16;
        f32x4 v = *(const f32x4*)(ip + (size_t)(r0 + r)*C + c0 + cx*4);
        float* d = T + r*65 + cx*4;
        d[0]=v[0]; d[1]=v[1]; d[2]=v[2]; d[3]=v[3];
    }
    __syncthreads();
    #pragma unroll
    for (int i = 0; i < 4; i++) {
        int c = rr + i*16;          // output row (= original column)
        int r = cx*4;
        u16x4 w = { f2bf(T[(r+0)*65 + c]), f2bf(T[(r+1)*65 + c]),
                    f2bf(T[(r+2)*65 + c]), f2bf(T[(r+3)*65 + c]) };
        *(u16x4*)(op + (size_t)(c0 + c)*R + r0 + r) = w;
    }
}

// ---------------------------------------------------------------- GEMM (A[M][K] bf16, B[N][K] bf16)
// MODE 0: out = bf16( gelu(acc + bias) )   MODE 1: out = f32( acc + bias )
template <int MODE>
__global__ __launch_bounds__(256, 2) void MoE_gemm_bt(
    const u16* __restrict__ Aall, const u16* __restrict__ Ball,
    void* __restrict__ Call, const float* __restrict__ biasAll,
    int M, int N, int K, int mTiles, int nTiles)
{
    int tilesPerE = mTiles * nTiles;
    int e  = blockIdx.x / tilesPerE;
    int t  = blockIdx.x % tilesPerE;
    int m0 = (t % mTiles) * 128;
    int n0 = (t / mTiles) * 128;
    const u16* A  = Aall + (size_t)e * M * K;
    const u16* Bm = Ball + (size_t)e * N * K;
    const float* bias = biasAll + (size_t)e * N;

    __shared__ u16 sA[128*32];
    __shared__ u16 sB[128*32];

    int tid = threadIdx.x;
    int lane = tid & 63, wid = tid >> 6;
    int wm = wid & 1, wn = wid >> 1;
    int l16 = lane & 15, quad = lane >> 4;

    int ch0 = tid, ch1 = 256 + tid;        // chunk ids (row = ch>>2, kc = ch&3)
    const u16* gA0 = A  + (size_t)(m0 + (ch0 >> 2))*K + (ch0 & 3)*8;
    const u16* gA1 = A  + (size_t)(m0 + (ch1 >> 2))*K + (ch1 & 3)*8;
    const u16* gB0 = Bm + (size_t)(n0 + (ch0 >> 2))*K + (ch0 & 3)*8;
    const u16* gB1 = Bm + (size_t)(n0 + (ch1 >> 2))*K + (ch1 & 3)*8;
    u16* dA0 = sA + (size_t)(tid & ~63) * 8;
    u16* dA1 = sA + (size_t)(256 + (tid & ~63)) * 8;
    u16* dB0 = sB + (size_t)(tid & ~63) * 8;
    u16* dB1 = sB + (size_t)(256 + (tid & ~63)) * 8;

    const u16* rA = sA + (wm*64 + l16)*32 + quad*8;
    const u16* rB = sB + (wn*64 + l16)*32 + quad*8;

    f32x4 acc[4][4] = {};
    int ksteps = K / 32;
    for (int kk = 0; kk < ksteps; ++kk) {
        async_cp16(gA0, dA0); async_cp16(gA1, dA1);
        async_cp16(gB0, dB0); async_cp16(gB1, dB1);
        gA0 += 32; gA1 += 32; gB0 += 32; gB1 += 32;
        __syncthreads();
        bf16x8 av[4], bv[4];
        #pragma unroll
        for (int i = 0; i < 4; i++) av[i] = __builtin_bit_cast(bf16x8, *(const u32x4*)(rA + i*512));
        #pragma unroll
        for (int j = 0; j < 4; j++) bv[j] = __builtin_bit_cast(bf16x8, *(const u32x4*)(rB + j*512));
        #pragma unroll
        for (int i = 0; i < 4; i++)
            #pragma unroll
            for (int j = 0; j < 4; j++)
                acc[i][j] = __builtin_amdgcn_mfma_f32_16x16x32_bf16(av[i], bv[j], acc[i][j], 0, 0, 0);
        __syncthreads();
    }

    if (MODE == 0) {
        u16* C = (u16*)Call + (size_t)e * M * N;
        #pragma unroll
        for (int i = 0; i < 4; i++) {
            int m = m0 + wm*64 + i*16 + quad*4;
            #pragma unroll
            for (int j = 0; j < 4; j++) {
                int n = n0 + wn*64 + j*16 + l16;
                float bn = bias[n];
                #pragma unroll
                for (int r = 0; r < 4; r++) {
                    float v = acc[i][j][r] + bn;
                    v = 0.5f * v * (1.0f + erff(v * 0.70710678118654752f));
                    C[(size_t)(m + r)*N + n] = f2bf(v);
                }
            }
        }
    } else {
        float* C = (float*)Call + (size_t)e * M * N;
        #pragma unroll
        for (int i = 0; i < 4; i++) {
            int m = m0 + wm*64 + i*16 + quad*4;
            #pragma unroll
            for (int j = 0; j < 4; j++) {
                int n = n0 + wn*64 + j*16 + l16;
                float bn = bias[n];
                #pragma unroll
                for (int r = 0; r < 4; r++)
                    C[(size_t)(m + r)*N + n] = acc[i][j][r] + bn;
            }
        }
    }
}

// ---------------------------------------------------------------- combine
__global__ __launch_bounds__(256) void MoE_combine(
    const float* __restrict__ EO,
    const int* __restrict__ i1, const int* __restrict__ i2,
    const int* __restrict__ p1, const int* __restrict__ p2,
    const float* __restrict__ g1f, const float* __restrict__ g2f,
    float* __restrict__ out)
{
    int tid = threadIdx.x, wid = tid >> 6, lane = tid & 63;
    int tok = blockIdx.x*4 + wid;
    int b = tok >> 11;
    float ga = g1f[tok], gb = g2f[tok];
    int ea = i1[tok], eb = i2[tok], pa = p1[tok], pb = p2[tok];
    f32x4 o[4] = {};
    if (ga > 0.0f) {
        const float* r = EO + ((size_t)(ea*BB + b)*CAP + pa) * DD;
        #pragma unroll
        for (int i = 0; i < 4; i++) {
            f32x4 v = *(const f32x4*)(r + (lane + 64*i)*4);
            o[i][0] += ga*v[0]; o[i][1] += ga*v[1]; o[i][2] += ga*v[2]; o[i][3] += ga*v[3];
        }
    }
    if (gb > 0.0f) {
        const float* r = EO + ((size_t)(eb*BB + b)*CAP + pb) * DD;
        #pragma unroll
        for (int i = 0; i < 4; i++) {
            f32x4 v = *(const f32x4*)(r + (lane + 64*i)*4);
            o[i][0] += gb*v[0]; o[i][1] += gb*v[1]; o[i][2] += gb*v[2]; o[i][3] += gb*v[3];
        }
    }
    float* w = out + (size_t)tok * DD;
    #pragma unroll
    for (int i = 0; i < 4; i++) *(f32x4*)(w + (lane + 64*i)*4) = o[i];
}

// ---------------------------------------------------------------- loss
__global__ void MoE_loss(const float* __restrict__ proxy, const float* __restrict__ cnt,
                         float* __restrict__ out)
{
    int t = threadIdx.x;
    float v = proxy[t] * cnt[t];
    for (int off = 32; off; off >>= 1) v += __shfl_down(v, off, 64);
    if (t == 0) out[0] = v * (0.01f / ((float)NN * (float)NN));
}

// ================================================================ launch
extern "C" void kernel_launch(void* const* d_in, const int* in_sizes, int n_in,
                              void* d_out, int out_size, void* d_ws, size_t ws_size,
                              hipStream_t stream) {
    const float* x  = (const float*)d_in[0];
    const float* wg = (const float*)d_in[1];
    const float* w1 = (const float*)d_in[2];
    const float* b1 = (const float*)d_in[3];
    const float* w2 = (const float*)d_in[4];
    const float* b2 = (const float*)d_in[5];
    const float* rp = (const float*)d_in[6];
    float* out = (float*)d_out;

    char* w = (char*)d_ws;
    auto alloc = [&](size_t bytes) -> char* {
        char* p = w; w += (bytes + 255) & ~(size_t)255; return p;
    };
    u16*   w1b  = (u16*)alloc((size_t)2*EE*DD*HH);          // [E][H][D] bf16
    u16*   w2b  = (u16*)alloc((size_t)2*EE*HH*DD);          // [E][D][H] bf16
    u16*   Abuf = (u16*)alloc((size_t)2*EE*MBC*DD);         // [E][M][K]
    u16*   Hbuf = (u16*)alloc((size_t)2*EE*MBC*HH);         // [E][M][H]
    float* EO   = (float*)alloc((size_t)4*EE*MBC*DD);       // [E][M][D]
    int*   i1   = (int*)alloc(4*NTOK);
    int*   i2   = (int*)alloc(4*NTOK);
    int*   keep = (int*)alloc(4*NTOK);
    int*   p1   = (int*)alloc(4*NTOK);
    int*   p2   = (int*)alloc(4*NTOK);
    float* g1   = (float*)alloc(4*NTOK);
    float* g2   = (float*)alloc(4*NTOK);
    float* g1f  = (float*)alloc(4*NTOK);
    float* g2f  = (float*)alloc(4*NTOK);
    int*   slot = (int*)alloc(4*EE*BB*CAP);
    float* stats = (float*)alloc(4*128);                    // proxy[64], cnt[64]
    float* proxy = stats;
    float* cnt   = stats + 64;

    MoE_zero_stats<<<1, 128, 0, stream>>>(stats);
    // w1: [E][1024][4096] -> [E][4096][1024]
    MoE_transpose_bf16<<<EE*16*64, 256, 0, stream>>>(w1, w1b, 1024, 4096, 16, 64);
    // w2: [E][4096][1024] -> [E][1024][4096]
    MoE_transpose_bf16<<<EE*64*16, 256, 0, stream>>>(w2, w2b, 4096, 1024, 64, 16);
    MoE_gating<<<NTOK/4, 256, 0, stream>>>(x, wg, rp, i1, i2, g1, g2, keep, proxy, cnt);
    MoE_scan<<<BB, 256, 0, stream>>>(i1, i2, keep, g1, g2, p1, p2, g1f, g2f, slot);
    MoE_dispatch<<<EE*BB*CAP/4, 256, 0, stream>>>(x, slot, Abuf);
    // GEMM1: [2560x1024] @ [1024x4096] -> gelu -> Hbuf
    MoE_gemm_bt<0><<<EE*20*32, 256, 0, stream>>>(Abuf, w1b, Hbuf, b1, MBC, HH, DD, 20, 32);
    // GEMM2: [2560x4096] @ [4096x1024] -> EO
    MoE_gemm_bt<1><<<EE*20*8, 256, 0, stream>>>(Hbuf, w2b, EO, b2, MBC, DD, HH, 20, 8);
    MoE_combine<<<NTOK/4, 256, 0, stream>>>(EO, i1, i2, p1, p2, g1f, g2f, out);
    MoE_loss<<<1, 64, 0, stream>>>(proxy, cnt, out + (size_t)NTOK*DD);
}

// Round 2
// 923.805 us; speedup vs baseline: 1.0848x; 1.0848x over previous
//
#include <hip/hip_runtime.h>
#include <hip/hip_bf16.h>
#include <math.h>

// Problem constants
#define BB 8
#define NN 2048
#define DD 1024
#define EE 8
#define HH 4096
#define CAP 320
#define NTOK (BB*NN)        // 16384
#define MBC (BB*CAP)        // 2560 rows per expert GEMM

typedef __bf16 bf16x8 __attribute__((ext_vector_type(8)));
typedef float f32x4 __attribute__((ext_vector_type(4)));
typedef unsigned u32x4 __attribute__((ext_vector_type(4)));
typedef unsigned short u16x4 __attribute__((ext_vector_type(4)));
typedef unsigned short u16;

__device__ __forceinline__ u16 f2bf(float f) {
    unsigned u = __builtin_bit_cast(unsigned, f);
    u += 0x7FFFu + ((u >> 16) & 1u);        // RNE
    return (u16)(u >> 16);
}

__device__ __forceinline__ void async_cp16(const void* g, void* l) {
    __builtin_amdgcn_global_load_lds((const __attribute__((address_space(1))) void*)g,
                                     (__attribute__((address_space(3))) void*)l,
                                     16, 0, 0);
}

// ---------------------------------------------------------------- zero stats
__global__ void MoE_zero_stats(float* stats) {
    if (threadIdx.x < 128) stats[threadIdx.x] = 0.0f;   // proxy[64] + cnt[64]
}

// ---------------------------------------------------------------- gating
__global__ __launch_bounds__(256) void MoE_gating(
    const float* __restrict__ x, const float* __restrict__ wg,
    const float* __restrict__ rp,
    int* __restrict__ i1o, int* __restrict__ i2o,
    float* __restrict__ g1o, float* __restrict__ g2o, int* __restrict__ keepo,
    float* __restrict__ proxy, float* __restrict__ cnt1)
{
    __shared__ float wgT[8*1024];
    __shared__ float sprox[8];
    __shared__ float scnt[8];
    int tid = threadIdx.x;
    {   // stage wg transposed: wgT[e][d]
        int d0 = tid*4;
        #pragma unroll
        for (int j = 0; j < 4; j++) {
            int d = d0 + j;
            f32x4 a = *(const f32x4*)(wg + d*8);
            f32x4 b = *(const f32x4*)(wg + d*8 + 4);
            wgT[0*1024+d]=a[0]; wgT[1*1024+d]=a[1]; wgT[2*1024+d]=a[2]; wgT[3*1024+d]=a[3];
            wgT[4*1024+d]=b[0]; wgT[5*1024+d]=b[1]; wgT[6*1024+d]=b[2]; wgT[7*1024+d]=b[3];
        }
    }
    if (tid < 8) { sprox[tid] = 0.0f; scnt[tid] = 0.0f; }
    __syncthreads();

    int wid = tid >> 6, lane = tid & 63;
    int tok = blockIdx.x*4 + wid;
    int b = tok >> 11;
    const float* xr = x + (size_t)tok * DD;

    double acc[8];
    #pragma unroll
    for (int e = 0; e < 8; e++) acc[e] = 0.0;
    for (int i = 0; i < 16; i++) {
        float xv = xr[i*64 + lane];
        #pragma unroll
        for (int e = 0; e < 8; e++)
            acc[e] += (double)xv * (double)wgT[e*1024 + i*64 + lane];
    }
    #pragma unroll
    for (int e = 0; e < 8; e++) {
        double v = acc[e];
        for (int off = 32; off; off >>= 1) v += __shfl_down(v, off, 64);
        acc[e] = v;
    }
    if (lane == 0) {
        float l[8];
        #pragma unroll
        for (int e = 0; e < 8; e++) l[e] = (float)acc[e];
        int i1 = 0;
        #pragma unroll
        for (int e = 1; e < 8; e++) if (l[e] > l[i1]) i1 = e;
        int i2 = (i1 == 0) ? 1 : 0;
        #pragma unroll
        for (int e = 0; e < 8; e++) if (e != i1 && l[e] > l[i2]) i2 = e;
        float mx = l[i1], p[8], s = 0.0f;
        #pragma unroll
        for (int e = 0; e < 8; e++) { p[e] = expf(l[e] - mx); s += p[e]; }
        float inv = 1.0f / s;
        #pragma unroll
        for (int e = 0; e < 8; e++) p[e] *= inv;
        float gate1 = p[i1], gate2 = p[i2];
        float denom = gate1 + gate2 + 1e-9f;
        float g1 = gate1 / denom, g2 = gate2 / denom;
        int keep = (rp[tok] < g2 / 0.2f) ? 1 : 0;
        i1o[tok] = i1; i2o[tok] = i2; g1o[tok] = g1; g2o[tok] = g2; keepo[tok] = keep;
        #pragma unroll
        for (int e = 0; e < 8; e++) atomicAdd(&sprox[e], p[e]);
        atomicAdd(&scnt[i1], 1.0f);
    }
    __syncthreads();
    if (tid < 8) {
        atomicAdd(&proxy[b*8 + tid], sprox[tid]);
        atomicAdd(&cnt1[b*8 + tid], scnt[tid]);
    }
}

// ---------------------------------------------------------------- scan (positions)
__global__ __launch_bounds__(256) void MoE_scan(
    const int* __restrict__ i1, const int* __restrict__ i2, const int* __restrict__ keep,
    const float* __restrict__ g1, const float* __restrict__ g2,
    int* __restrict__ p1o, int* __restrict__ p2o,
    float* __restrict__ g1f, float* __restrict__ g2f,
    int* __restrict__ slot_token)
{
    int b = blockIdx.x, t = threadIdx.x;
    __shared__ unsigned long long s0[256], s1[256];
    for (int s = t; s < EE*CAP; s += 256) {
        int e = s / CAP, c = s % CAP;
        slot_token[(e*BB + b)*CAP + c] = -1;
    }
    int base = b*NN + t*8;

    // ---- phase 1: mask1 ----
    int e1v[8];
    unsigned long long u0 = 0, u1 = 0;
    #pragma unroll
    for (int j = 0; j < 8; j++) {
        int e = i1[base + j]; e1v[j] = e;
        if (e < 4) u0 += 1ull << (e*16); else u1 += 1ull << ((e-4)*16);
    }
    s0[t] = u0; s1[t] = u1;
    __syncthreads();
    for (int off = 1; off < 256; off <<= 1) {
        unsigned long long a0 = 0, a1 = 0;
        if (t >= off) { a0 = s0[t-off]; a1 = s1[t-off]; }
        __syncthreads();
        s0[t] += a0; s1[t] += a1;
        __syncthreads();
    }
    unsigned long long t0 = s0[255], t1 = s1[255];
    unsigned long long x0 = s0[t] - u0, x1 = s1[t] - u1;
    int run[8], mc[8];
    #pragma unroll
    for (int e = 0; e < 8; e++) {
        run[e] = (int)((e < 4 ? (x0 >> (e*16)) : (x1 >> ((e-4)*16))) & 0xFFFF);
        int tot = (int)((e < 4 ? (t0 >> (e*16)) : (t1 >> ((e-4)*16))) & 0xFFFF);
        mc[e] = tot < CAP ? tot : CAP;
    }
    #pragma unroll
    for (int j = 0; j < 8; j++) {
        int e = e1v[j];
        int p = run[e]++;
        bool v = p < CAP;
        p1o[base + j] = p;
        g1f[base + j] = v ? g1[base + j] : 0.0f;
        if (v) slot_token[(e*BB + b)*CAP + p] = t*8 + j;
    }
    __syncthreads();

    // ---- phase 2: mask2 (offset by mask1_count) ----
    int e2v[8], kv[8];
    u0 = 0; u1 = 0;
    #pragma unroll
    for (int j = 0; j < 8; j++) {
        int e = i2[base + j]; e2v[j] = e;
        int k = keep[base + j]; kv[j] = k;
        if (k) { if (e < 4) u0 += 1ull << (e*16); else u1 += 1ull << ((e-4)*16); }
    }
    s0[t] = u0; s1[t] = u1;
    __syncthreads();
    for (int off = 1; off < 256; off <<= 1) {
        unsigned long long a0 = 0, a1 = 0;
        if (t >= off) { a0 = s0[t-off]; a1 = s1[t-off]; }
        __syncthreads();
        s0[t] += a0; s1[t] += a1;
        __syncthreads();
    }
    x0 = s0[t] - u0; x1 = s1[t] - u1;
    #pragma unroll
    for (int e = 0; e < 8; e++)
        run[e] = mc[e] + (int)((e < 4 ? (x0 >> (e*16)) : (x1 >> ((e-4)*16))) & 0xFFFF);
    #pragma unroll
    for (int j = 0; j < 8; j++) {
        if (kv[j]) {
            int e = e2v[j];
            int p = run[e]++;
            bool v = p < CAP;
            p2o[base + j] = p;
            g2f[base + j] = v ? g2[base + j] : 0.0f;
            if (v) slot_token[(e*BB + b)*CAP + p] = t*8 + j;
        } else {
            p2o[base + j] = 0;
            g2f[base + j] = 0.0f;
        }
    }
}

// ---------------------------------------------------------------- dispatch gather -> bf16
__global__ __launch_bounds__(256) void MoE_dispatch(
    const float* __restrict__ x, const int* __restrict__ slot_token,
    u16* __restrict__ Abuf)
{
    int tid = threadIdx.x, wid = tid >> 6, lane = tid & 63;
    int slot = blockIdx.x*4 + wid;            // (e*8+b)*320+c
    int b = (slot % (BB*CAP)) / CAP;
    int tok = slot_token[slot];
    u16* dst = Abuf + (size_t)slot * DD;
    if (tok >= 0) {
        const float* src = x + ((size_t)b*NN + tok) * DD;
        #pragma unroll
        for (int i = 0; i < 4; i++) {
            f32x4 v = *(const f32x4*)(src + (lane + 64*i)*4);
            u16x4 w = { f2bf(v[0]), f2bf(v[1]), f2bf(v[2]), f2bf(v[3]) };
            *(u16x4*)(dst + (lane + 64*i)*4) = w;
        }
    } else {
        u16x4 z = {0,0,0,0};
        #pragma unroll
        for (int i = 0; i < 4; i++) *(u16x4*)(dst + (lane + 64*i)*4) = z;
    }
}

// ---------------------------------------------------------------- weight transpose fp32[E][R][C] -> bf16[E][C][R]
__global__ __launch_bounds__(256) void MoE_transpose_bf16(
    const float* __restrict__ in, u16* __restrict__ out,
    int R, int C, int rTiles, int cTiles)
{
    int tilesPerE = rTiles * cTiles;
    int e = blockIdx.x / tilesPerE;
    int t = blockIdx.x % tilesPerE;
    int r0 = (t / cTiles) * 64, c0 = (t % cTiles) * 64;
    const float* ip = in + (size_t)e * R * C;
    u16* op = out + (size_t)e * R * C;
    __shared__ float T[64*65];
    int tid = threadIdx.x;
    int rr = tid >> 4, cx = tid & 15;
    #pragma unroll
    for (int i = 0; i < 4; i++) {
        int r = rr + i*16;
        f32x4 v = *(const f32x4*)(ip + (size_t)(r0 + r)*C + c0 + cx*4);
        float* d = T + r*65 + cx*4;
        d[0]=v[0]; d[1]=v[1]; d[2]=v[2]; d[3]=v[3];
    }
    __syncthreads();
    #pragma unroll
    for (int i = 0; i < 4; i++) {
        int c = rr + i*16;          // output row (= original column)
        int r = cx*4;
        u16x4 w = { f2bf(T[(r+0)*65 + c]), f2bf(T[(r+1)*65 + c]),
                    f2bf(T[(r+2)*65 + c]), f2bf(T[(r+3)*65 + c]) };
        *(u16x4*)(op + (size_t)(c0 + c)*R + r0 + r) = w;
    }
}

// ---------------------------------------------------------------- GEMM (A[M][K] bf16, B[N][K] bf16)
// expert = blockIdx&7 (XCD-aligned); tiles within expert: GROUP_M=8 supertiles,
// n fastest, serpentine. LDS K-chunks XOR-swizzled (kc ^= row&3) for bank spread.
// MODE 0: out = bf16( gelu(acc + bias) )   MODE 1: out = f32( acc + bias )
template <int MODE>
__global__ __launch_bounds__(256, 2) void MoE_gemm_bt(
    const u16* __restrict__ Aall, const u16* __restrict__ Ball,
    void* __restrict__ Call, const float* __restrict__ biasAll,
    int M, int N, int K, int mTiles, int nTiles)
{
    int bid = blockIdx.x;
    int e = bid & 7;
    int i = bid >> 3;                 // tile index within expert
    const int GM = 8;
    int group = i / (GM*nTiles);
    int gm = mTiles - group*GM; if (gm > GM) gm = GM;
    int rem = i - group*GM*nTiles;
    int n_ = rem / gm;
    int mm = rem % gm;
    if (n_ & 1) mm = gm - 1 - mm;     // serpentine
    int m0 = (group*GM + mm) * 128;
    int n0 = n_ * 128;

    const u16* A  = Aall + (size_t)e * M * K;
    const u16* Bm = Ball + (size_t)e * N * K;
    const float* bias = biasAll + (size_t)e * N;

    __shared__ u16 sA[128*32];
    __shared__ u16 sB[128*32];

    int tid = threadIdx.x;
    int lane = tid & 63, wid = tid >> 6;
    int wm = wid & 1, wn = wid >> 1;
    int l16 = lane & 15, quad = lane >> 4;

    // staging: chunk ch covers (row=ch>>2, slot kc=ch&3); lane fetches the
    // XOR-swizzled global chunk (kc ^ row&3) so LDS slot layout is bank-spread
    int ch0 = tid, ch1 = 256 + tid;
    int r0c = ch0 >> 2, c0c = (ch0 & 3) ^ (r0c & 3);
    int r1c = ch1 >> 2, c1c = (ch1 & 3) ^ (r1c & 3);
    const u16* gA0 = A  + (size_t)(m0 + r0c)*K + c0c*8;
    const u16* gA1 = A  + (size_t)(m0 + r1c)*K + c1c*8;
    const u16* gB0 = Bm + (size_t)(n0 + r0c)*K + c0c*8;
    const u16* gB1 = Bm + (size_t)(n0 + r1c)*K + c1c*8;
    u16* dA0 = sA + (size_t)(tid & ~63) * 8;
    u16* dA1 = sA + (size_t)(256 + (tid & ~63)) * 8;
    u16* dB0 = sB + (size_t)(tid & ~63) * 8;
    u16* dB1 = sB + (size_t)(256 + (tid & ~63)) * 8;

    // readers: fragment row r = (wm*64 + i*16 + l16) -> r&3 == l16&3;
    // global chunk `quad` sits in LDS slot (quad ^ (l16&3))
    const u16* rA = sA + (wm*64 + l16)*32 + ((quad ^ (l16 & 3)) * 8);
    const u16* rB = sB + (wn*64 + l16)*32 + ((quad ^ (l16 & 3)) * 8);

    f32x4 acc[4][4] = {};
    int ksteps = K / 32;
    for (int kk = 0; kk < ksteps; ++kk) {
        async_cp16(gA0, dA0); async_cp16(gA1, dA1);
        async_cp16(gB0, dB0); async_cp16(gB1, dB1);
        gA0 += 32; gA1 += 32; gB0 += 32; gB1 += 32;
        __syncthreads();
        bf16x8 av[4], bv[4];
        #pragma unroll
        for (int i2 = 0; i2 < 4; i2++) av[i2] = __builtin_bit_cast(bf16x8, *(const u32x4*)(rA + i2*512));
        #pragma unroll
        for (int j = 0; j < 4; j++) bv[j] = __builtin_bit_cast(bf16x8, *(const u32x4*)(rB + j*512));
        #pragma unroll
        for (int i2 = 0; i2 < 4; i2++)
            #pragma unroll
            for (int j = 0; j < 4; j++)
                acc[i2][j] = __builtin_amdgcn_mfma_f32_16x16x32_bf16(av[i2], bv[j], acc[i2][j], 0, 0, 0);
        __syncthreads();
    }

    if (MODE == 0) {
        u16* C = (u16*)Call + (size_t)e * M * N;
        #pragma unroll
        for (int i2 = 0; i2 < 4; i2++) {
            int m = m0 + wm*64 + i2*16 + quad*4;
            #pragma unroll
            for (int j = 0; j < 4; j++) {
                int n = n0 + wn*64 + j*16 + l16;
                float bn = bias[n];
                #pragma unroll
                for (int r = 0; r < 4; r++) {
                    float v = acc[i2][j][r] + bn;
                    v = 0.5f * v * (1.0f + erff(v * 0.70710678118654752f));
                    C[(size_t)(m + r)*N + n] = f2bf(v);
                }
            }
        }
    } else {
        float* C = (float*)Call + (size_t)e * M * N;
        #pragma unroll
        for (int i2 = 0; i2 < 4; i2++) {
            int m = m0 + wm*64 + i2*16 + quad*4;
            #pragma unroll
            for (int j = 0; j < 4; j++) {
                int n = n0 + wn*64 + j*16 + l16;
                float bn = bias[n];
                #pragma unroll
                for (int r = 0; r < 4; r++)
                    C[(size_t)(m + r)*N + n] = acc[i2][j][r] + bn;
            }
        }
    }
}

// ---------------------------------------------------------------- combine
__global__ __launch_bounds__(256) void MoE_combine(
    const float* __restrict__ EO,
    const int* __restrict__ i1, const int* __restrict__ i2,
    const int* __restrict__ p1, const int* __restrict__ p2,
    const float* __restrict__ g1f, const float* __restrict__ g2f,
    float* __restrict__ out)
{
    int tid = threadIdx.x, wid = tid >> 6, lane = tid & 63;
    int tok = blockIdx.x*4 + wid;
    int b = tok >> 11;
    float ga = g1f[tok], gb = g2f[tok];
    int ea = i1[tok], eb = i2[tok], pa = p1[tok], pb = p2[tok];
    f32x4 o[4] = {};
    if (ga > 0.0f) {
        const float* r = EO + ((size_t)(ea*BB + b)*CAP + pa) * DD;
        #pragma unroll
        for (int i = 0; i < 4; i++) {
            f32x4 v = *(const f32x4*)(r + (lane + 64*i)*4);
            o[i][0] += ga*v[0]; o[i][1] += ga*v[1]; o[i][2] += ga*v[2]; o[i][3] += ga*v[3];
        }
    }
    if (gb > 0.0f) {
        const float* r = EO + ((size_t)(eb*BB + b)*CAP + pb) * DD;
        #pragma unroll
        for (int i = 0; i < 4; i++) {
            f32x4 v = *(const f32x4*)(r + (lane + 64*i)*4);
            o[i][0] += gb*v[0]; o[i][1] += gb*v[1]; o[i][2] += gb*v[2]; o[i][3] += gb*v[3];
        }
    }
    float* w = out + (size_t)tok * DD;
    #pragma unroll
    for (int i = 0; i < 4; i++) *(f32x4*)(w + (lane + 64*i)*4) = o[i];
}

// ---------------------------------------------------------------- loss
__global__ void MoE_loss(const float* __restrict__ proxy, const float* __restrict__ cnt,
                         float* __restrict__ out)
{
    int t = threadIdx.x;
    float v = proxy[t] * cnt[t];
    for (int off = 32; off; off >>= 1) v += __shfl_down(v, off, 64);
    if (t == 0) out[0] = v * (0.01f / ((float)NN * (float)NN));
}

// ================================================================ launch
extern "C" void kernel_launch(void* const* d_in, const int* in_sizes, int n_in,
                              void* d_out, int out_size, void* d_ws, size_t ws_size,
                              hipStream_t stream) {
    const float* x  = (const float*)d_in[0];
    const float* wg = (const float*)d_in[1];
    const float* w1 = (const float*)d_in[2];
    const float* b1 = (const float*)d_in[3];
    const float* w2 = (const float*)d_in[4];
    const float* b2 = (const float*)d_in[5];
    const float* rp = (const float*)d_in[6];
    float* out = (float*)d_out;

    char* w = (char*)d_ws;
    auto alloc = [&](size_t bytes) -> char* {
        char* p = w; w += (bytes + 255) & ~(size_t)255; return p;
    };
    u16*   w1b  = (u16*)alloc((size_t)2*EE*DD*HH);          // [E][H][D] bf16
    u16*   w2b  = (u16*)alloc((size_t)2*EE*HH*DD);          // [E][D][H] bf16
    u16*   Abuf = (u16*)alloc((size_t)2*EE*MBC*DD);         // [E][M][K]
    u16*   Hbuf = (u16*)alloc((size_t)2*EE*MBC*HH);         // [E][M][H]
    float* EO   = (float*)alloc((size_t)4*EE*MBC*DD);       // [E][M][D]
    int*   i1   = (int*)alloc(4*NTOK);
    int*   i2   = (int*)alloc(4*NTOK);
    int*   keep = (int*)alloc(4*NTOK);
    int*   p1   = (int*)alloc(4*NTOK);
    int*   p2   = (int*)alloc(4*NTOK);
    float* g1   = (float*)alloc(4*NTOK);
    float* g2   = (float*)alloc(4*NTOK);
    float* g1f  = (float*)alloc(4*NTOK);
    float* g2f  = (float*)alloc(4*NTOK);
    int*   slot = (int*)alloc(4*EE*BB*CAP);
    float* stats = (float*)alloc(4*128);                    // proxy[64], cnt[64]
    float* proxy = stats;
    float* cnt   = stats + 64;

    MoE_zero_stats<<<1, 128, 0, stream>>>(stats);
    // w1: [E][1024][4096] -> [E][4096][1024]
    MoE_transpose_bf16<<<EE*16*64, 256, 0, stream>>>(w1, w1b, 1024, 4096, 16, 64);
    // w2: [E][4096][1024] -> [E][1024][4096]
    MoE_transpose_bf16<<<EE*64*16, 256, 0, stream>>>(w2, w2b, 4096, 1024, 64, 16);
    MoE_gating<<<NTOK/4, 256, 0, stream>>>(x, wg, rp, i1, i2, g1, g2, keep, proxy, cnt);
    MoE_scan<<<BB, 256, 0, stream>>>(i1, i2, keep, g1, g2, p1, p2, g1f, g2f, slot);
    MoE_dispatch<<<EE*BB*CAP/4, 256, 0, stream>>>(x, slot, Abuf);
    // GEMM1: [2560x1024] @ [1024x4096]^T-layout -> gelu -> Hbuf
    MoE_gemm_bt<0><<<EE*20*32, 256, 0, stream>>>(Abuf, w1b, Hbuf, b1, MBC, HH, DD, 20, 32);
    // GEMM2: [2560x4096] @ [4096x1024]^T-layout -> EO
    MoE_gemm_bt<1><<<EE*20*8, 256, 0, stream>>>(Hbuf, w2b, EO, b2, MBC, DD, HH, 20, 8);
    MoE_combine<<<NTOK/4, 256, 0, stream>>>(EO, i1, i2, p1, p2, g1f, g2f, out);
    MoE_loss<<<1, 64, 0, stream>>>(proxy, cnt, out + (size_t)NTOK*DD);
}

// Round 3
// 859.869 us; speedup vs baseline: 1.1655x; 1.0744x over previous
//
#include <hip/hip_runtime.h>
#include <hip/hip_bf16.h>
#include <math.h>

// Problem constants
#define BB 8
#define NN 2048
#define DD 1024
#define EE 8
#define HH 4096
#define CAP 320
#define NTOK (BB*NN)        // 16384
#define MBC (BB*CAP)        // 2560 rows per expert GEMM

typedef __bf16 bf16x8 __attribute__((ext_vector_type(8)));
typedef float f32x4 __attribute__((ext_vector_type(4)));
typedef unsigned u32x4 __attribute__((ext_vector_type(4)));
typedef unsigned short u16x4 __attribute__((ext_vector_type(4)));
typedef unsigned short u16x8v __attribute__((ext_vector_type(8)));
typedef unsigned short u16;

__device__ __forceinline__ u16 f2bf(float f) {
    unsigned u = __builtin_bit_cast(unsigned, f);
    u += 0x7FFFu + ((u >> 16) & 1u);        // RNE
    return (u16)(u >> 16);
}

__device__ __forceinline__ void async_cp16(const void* g, void* l) {
    __builtin_amdgcn_global_load_lds((const __attribute__((address_space(1))) void*)g,
                                     (__attribute__((address_space(3))) void*)l,
                                     16, 0, 0);
}

// tanh-form gelu: max |err| vs exact ~3e-4, ~8 VALU ops
__device__ __forceinline__ float gelu_fast(float v) {
    float u = v * (0.7978845608f + 0.0356774081f * v * v);
    u = fminf(fmaxf(u, -30.0f), 30.0f);
    float ex = __expf(-2.0f * u);
    float th = (1.0f - ex) / (1.0f + ex);
    return 0.5f * v * (1.0f + th);
}

// ---------------------------------------------------------------- zero stats
__global__ void MoE_zero_stats(float* stats) {
    if (threadIdx.x < 128) stats[threadIdx.x] = 0.0f;   // proxy[64] + cnt[64]
}

// ---------------------------------------------------------------- gating (+ zero-init of out rows)
__global__ __launch_bounds__(256) void MoE_gating(
    const float* __restrict__ x, const float* __restrict__ wg,
    const float* __restrict__ rp,
    int* __restrict__ i1o, int* __restrict__ i2o,
    float* __restrict__ g1o, float* __restrict__ g2o, int* __restrict__ keepo,
    float* __restrict__ proxy, float* __restrict__ cnt1,
    float* __restrict__ out_zero)
{
    __shared__ float wgT[8*1024];
    __shared__ float sprox[8];
    __shared__ float scnt[8];
    int tid = threadIdx.x;
    {   // zero this block's 4 output rows (fused combine accumulates into them)
        f32x4 z = {0,0,0,0};
        f32x4* dst = (f32x4*)(out_zero + (size_t)blockIdx.x * 4 * DD);
        #pragma unroll
        for (int i = 0; i < 4; i++) dst[tid + 256*i] = z;
    }
    {   // stage wg transposed: wgT[e][d]
        int d0 = tid*4;
        #pragma unroll
        for (int j = 0; j < 4; j++) {
            int d = d0 + j;
            f32x4 a = *(const f32x4*)(wg + d*8);
            f32x4 b = *(const f32x4*)(wg + d*8 + 4);
            wgT[0*1024+d]=a[0]; wgT[1*1024+d]=a[1]; wgT[2*1024+d]=a[2]; wgT[3*1024+d]=a[3];
            wgT[4*1024+d]=b[0]; wgT[5*1024+d]=b[1]; wgT[6*1024+d]=b[2]; wgT[7*1024+d]=b[3];
        }
    }
    if (tid < 8) { sprox[tid] = 0.0f; scnt[tid] = 0.0f; }
    __syncthreads();

    int wid = tid >> 6, lane = tid & 63;
    int tok = blockIdx.x*4 + wid;
    int b = tok >> 11;
    const float* xr = x + (size_t)tok * DD;

    double acc[8];
    #pragma unroll
    for (int e = 0; e < 8; e++) acc[e] = 0.0;
    for (int i = 0; i < 16; i++) {
        float xv = xr[i*64 + lane];
        #pragma unroll
        for (int e = 0; e < 8; e++)
            acc[e] += (double)xv * (double)wgT[e*1024 + i*64 + lane];
    }
    #pragma unroll
    for (int e = 0; e < 8; e++) {
        double v = acc[e];
        for (int off = 32; off; off >>= 1) v += __shfl_down(v, off, 64);
        acc[e] = v;
    }
    if (lane == 0) {
        float l[8];
        #pragma unroll
        for (int e = 0; e < 8; e++) l[e] = (float)acc[e];
        int i1 = 0;
        #pragma unroll
        for (int e = 1; e < 8; e++) if (l[e] > l[i1]) i1 = e;
        int i2 = (i1 == 0) ? 1 : 0;
        #pragma unroll
        for (int e = 0; e < 8; e++) if (e != i1 && l[e] > l[i2]) i2 = e;
        float mx = l[i1], p[8], s = 0.0f;
        #pragma unroll
        for (int e = 0; e < 8; e++) { p[e] = expf(l[e] - mx); s += p[e]; }
        float inv = 1.0f / s;
        #pragma unroll
        for (int e = 0; e < 8; e++) p[e] *= inv;
        float gate1 = p[i1], gate2 = p[i2];
        float denom = gate1 + gate2 + 1e-9f;
        float g1 = gate1 / denom, g2 = gate2 / denom;
        int keep = (rp[tok] < g2 / 0.2f) ? 1 : 0;
        i1o[tok] = i1; i2o[tok] = i2; g1o[tok] = g1; g2o[tok] = g2; keepo[tok] = keep;
        #pragma unroll
        for (int e = 0; e < 8; e++) atomicAdd(&sprox[e], p[e]);
        atomicAdd(&scnt[i1], 1.0f);
    }
    __syncthreads();
    if (tid < 8) {
        atomicAdd(&proxy[b*8 + tid], sprox[tid]);
        atomicAdd(&cnt1[b*8 + tid], scnt[tid]);
    }
}

// ---------------------------------------------------------------- scan (positions -> slot map + slot gates)
__global__ __launch_bounds__(256) void MoE_scan(
    const int* __restrict__ i1, const int* __restrict__ i2, const int* __restrict__ keep,
    const float* __restrict__ g1, const float* __restrict__ g2,
    int* __restrict__ slot_token, float* __restrict__ slot_gate)
{
    int b = blockIdx.x, t = threadIdx.x;
    __shared__ unsigned long long s0[256], s1[256];
    for (int s = t; s < EE*CAP; s += 256) {
        int e = s / CAP, c = s % CAP;
        slot_token[(e*BB + b)*CAP + c] = -1;
    }
    int base = b*NN + t*8;

    // ---- phase 1: mask1 ----
    int e1v[8];
    unsigned long long u0 = 0, u1 = 0;
    #pragma unroll
    for (int j = 0; j < 8; j++) {
        int e = i1[base + j]; e1v[j] = e;
        if (e < 4) u0 += 1ull << (e*16); else u1 += 1ull << ((e-4)*16);
    }
    s0[t] = u0; s1[t] = u1;
    __syncthreads();
    for (int off = 1; off < 256; off <<= 1) {
        unsigned long long a0 = 0, a1 = 0;
        if (t >= off) { a0 = s0[t-off]; a1 = s1[t-off]; }
        __syncthreads();
        s0[t] += a0; s1[t] += a1;
        __syncthreads();
    }
    unsigned long long t0 = s0[255], t1 = s1[255];
    unsigned long long x0 = s0[t] - u0, x1 = s1[t] - u1;
    int run[8], mc[8];
    #pragma unroll
    for (int e = 0; e < 8; e++) {
        run[e] = (int)((e < 4 ? (x0 >> (e*16)) : (x1 >> ((e-4)*16))) & 0xFFFF);
        int tot = (int)((e < 4 ? (t0 >> (e*16)) : (t1 >> ((e-4)*16))) & 0xFFFF);
        mc[e] = tot < CAP ? tot : CAP;
    }
    #pragma unroll
    for (int j = 0; j < 8; j++) {
        int e = e1v[j];
        int p = run[e]++;
        if (p < CAP) {
            slot_token[(e*BB + b)*CAP + p] = t*8 + j;
            slot_gate[(e*BB + b)*CAP + p] = g1[base + j];
        }
    }
    __syncthreads();

    // ---- phase 2: mask2 (offset by mask1_count) ----
    int e2v[8], kv[8];
    u0 = 0; u1 = 0;
    #pragma unroll
    for (int j = 0; j < 8; j++) {
        int e = i2[base + j]; e2v[j] = e;
        int k = keep[base + j]; kv[j] = k;
        if (k) { if (e < 4) u0 += 1ull << (e*16); else u1 += 1ull << ((e-4)*16); }
    }
    s0[t] = u0; s1[t] = u1;
    __syncthreads();
    for (int off = 1; off < 256; off <<= 1) {
        unsigned long long a0 = 0, a1 = 0;
        if (t >= off) { a0 = s0[t-off]; a1 = s1[t-off]; }
        __syncthreads();
        s0[t] += a0; s1[t] += a1;
        __syncthreads();
    }
    x0 = s0[t] - u0; x1 = s1[t] - u1;
    #pragma unroll
    for (int e = 0; e < 8; e++)
        run[e] = mc[e] + (int)((e < 4 ? (x0 >> (e*16)) : (x1 >> ((e-4)*16))) & 0xFFFF);
    #pragma unroll
    for (int j = 0; j < 8; j++) {
        if (kv[j]) {
            int e = e2v[j];
            int p = run[e]++;
            if (p < CAP) {
                slot_token[(e*BB + b)*CAP + p] = t*8 + j;
                slot_gate[(e*BB + b)*CAP + p] = g2[base + j];
            }
        }
    }
}

// ---------------------------------------------------------------- dispatch gather -> bf16
__global__ __launch_bounds__(256) void MoE_dispatch(
    const float* __restrict__ x, const int* __restrict__ slot_token,
    u16* __restrict__ Abuf)
{
    int tid = threadIdx.x, wid = tid >> 6, lane = tid & 63;
    int slot = blockIdx.x*4 + wid;            // (e*8+b)*320+c
    int b = (slot % (BB*CAP)) / CAP;
    int tok = slot_token[slot];
    u16* dst = Abuf + (size_t)slot * DD;
    if (tok >= 0) {
        const float* src = x + ((size_t)b*NN + tok) * DD;
        #pragma unroll
        for (int i = 0; i < 4; i++) {
            f32x4 v = *(const f32x4*)(src + (lane + 64*i)*4);
            u16x4 w = { f2bf(v[0]), f2bf(v[1]), f2bf(v[2]), f2bf(v[3]) };
            *(u16x4*)(dst + (lane + 64*i)*4) = w;
        }
    } else {
        u16x4 z = {0,0,0,0};
        #pragma unroll
        for (int i = 0; i < 4; i++) *(u16x4*)(dst + (lane + 64*i)*4) = z;
    }
}

// ---------------------------------------------------------------- weight transpose fp32[E][R][C] -> bf16[E][C][R]
__global__ __launch_bounds__(256) void MoE_transpose_bf16(
    const float* __restrict__ in, u16* __restrict__ out,
    int R, int C, int rTiles, int cTiles)
{
    int tilesPerE = rTiles * cTiles;
    int e = blockIdx.x / tilesPerE;
    int t = blockIdx.x % tilesPerE;
    int r0 = (t / cTiles) * 64, c0 = (t % cTiles) * 64;
    const float* ip = in + (size_t)e * R * C;
    u16* op = out + (size_t)e * R * C;
    __shared__ float T[64*65];
    int tid = threadIdx.x;
    {
        int rr = tid >> 4, cx = tid & 15;
        #pragma unroll
        for (int i = 0; i < 4; i++) {
            int r = rr + i*16;
            f32x4 v = *(const f32x4*)(ip + (size_t)(r0 + r)*C + c0 + cx*4);
            float* d = T + r*65 + cx*4;
            d[0]=v[0]; d[1]=v[1]; d[2]=v[2]; d[3]=v[3];
        }
    }
    __syncthreads();
    {   // 16B/lane writes: lane handles 8 consecutive output elements
        int cw = tid >> 3, rx = tid & 7;          // cw 0..31, rx 0..7
        int r = rx*8;
        #pragma unroll
        for (int i = 0; i < 2; i++) {
            int c = cw + i*32;                    // output row = original column
            u16x8v w;
            #pragma unroll
            for (int jj = 0; jj < 8; jj++) w[jj] = f2bf(T[(r+jj)*65 + c]);
            *(u16x8v*)(op + (size_t)(c0 + c)*R + r0 + r) = w;
        }
    }
}

// ---------------------------------------------------------------- GEMM (A[M][K] bf16, B[N][K] bf16), BK=64
// expert = blockIdx&7 (XCD-aligned); GROUP_M=8 supertiles, serpentine.
// LDS 8-slot XOR swizzle (slot = kchunk ^ (row&7)) -> 2-way (free) ds_read pattern.
// MODE 0: Hbuf = bf16(gelu(acc+bias)).  MODE 1: fused combine — atomicAdd g*(acc+bias) into out.
template <int MODE>
__global__ __launch_bounds__(256, 3) void MoE_gemm_bt(
    const u16* __restrict__ Aall, const u16* __restrict__ Ball,
    void* __restrict__ Call, const float* __restrict__ biasAll,
    const int* __restrict__ slot_token, const float* __restrict__ slot_gate,
    int M, int N, int K, int mTiles, int nTiles)
{
    int bid = blockIdx.x;
    int e = bid & 7;
    int i = bid >> 3;                 // tile index within expert
    const int GM = 8;
    int group = i / (GM*nTiles);
    int gm = mTiles - group*GM; if (gm > GM) gm = GM;
    int rem = i - group*GM*nTiles;
    int n_ = rem / gm;
    int mm = rem % gm;
    if (n_ & 1) mm = gm - 1 - mm;     // serpentine
    int m0 = (group*GM + mm) * 128;
    int n0 = n_ * 128;

    const u16* A  = Aall + (size_t)e * M * K;
    const u16* Bm = Ball + (size_t)e * N * K;
    const float* bias = biasAll + (size_t)e * N;

    __shared__ u16 sA[128*64];
    __shared__ u16 sB[128*64];

    int tid = threadIdx.x;
    int lane = tid & 63, wid = tid >> 6;
    int wm = wid & 1, wn = wid >> 1;
    int l16 = lane & 15, quad = lane >> 4;

    // staging: chunk ch in [0,1024): row=ch>>3, LDS slot=ch&7 at linear pos ch*16B;
    // lane fetches global k-chunk gc = (ch&7)^(row&7)  (XOR swizzle)
    const u16* gA[4]; const u16* gB[4]; u16* dA[4]; u16* dB[4];
    #pragma unroll
    for (int l = 0; l < 4; l++) {
        int ch = l*256 + tid;
        int row = ch >> 3;
        int gc  = (ch & 7) ^ (row & 7);
        gA[l] = A  + (size_t)(m0 + row)*K + gc*8;
        gB[l] = Bm + (size_t)(n0 + row)*K + gc*8;
        dA[l] = sA + (size_t)(l*256 + (tid & ~63)) * 8;
        dB[l] = sB + (size_t)(l*256 + (tid & ~63)) * 8;
    }

    // readers: row r wants global chunk g -> LDS slot g^(r&7); r&7 == l16&7 here
    int rbaseA = (wm*64 + l16)*64;
    int rbaseB = (wn*64 + l16)*64;
    int sw = l16 & 7;
    int swz0 = ((0*4 + quad) ^ sw) * 8;
    int swz1 = ((1*4 + quad) ^ sw) * 8;

    f32x4 acc[4][4] = {};
    int ksteps = K / 64;
    for (int kk = 0; kk < ksteps; ++kk) {
        #pragma unroll
        for (int l = 0; l < 4; l++) {
            async_cp16(gA[l], dA[l]);
            async_cp16(gB[l], dB[l]);
            gA[l] += 64; gB[l] += 64;
        }
        __syncthreads();
        #pragma unroll
        for (int h = 0; h < 2; h++) {
            int swz = h ? swz1 : swz0;
            bf16x8 av[4], bv[4];
            #pragma unroll
            for (int i2 = 0; i2 < 4; i2++) av[i2] = __builtin_bit_cast(bf16x8, *(const u32x4*)(sA + rbaseA + i2*1024 + swz));
            #pragma unroll
            for (int j = 0; j < 4; j++) bv[j] = __builtin_bit_cast(bf16x8, *(const u32x4*)(sB + rbaseB + j*1024 + swz));
            #pragma unroll
            for (int i2 = 0; i2 < 4; i2++)
                #pragma unroll
                for (int j = 0; j < 4; j++)
                    acc[i2][j] = __builtin_amdgcn_mfma_f32_16x16x32_bf16(av[i2], bv[j], acc[i2][j], 0, 0, 0);
        }
        __syncthreads();
    }

    if (MODE == 0) {
        u16* C = (u16*)Call + (size_t)e * M * N;
        #pragma unroll
        for (int i2 = 0; i2 < 4; i2++) {
            int m = m0 + wm*64 + i2*16 + quad*4;
            #pragma unroll
            for (int j = 0; j < 4; j++) {
                int n = n0 + wn*64 + j*16 + l16;
                float bn = bias[n];
                #pragma unroll
                for (int r = 0; r < 4; r++) {
                    float v = acc[i2][j][r] + bn;
                    C[(size_t)(m + r)*N + n] = f2bf(gelu_fast(v));
                }
            }
        }
    } else {
        float* outp = (float*)Call;
        float bn[4];
        #pragma unroll
        for (int j = 0; j < 4; j++) bn[j] = bias[n0 + wn*64 + j*16 + l16];
        #pragma unroll
        for (int i2 = 0; i2 < 4; i2++) {
            #pragma unroll
            for (int r = 0; r < 4; r++) {
                int mr = m0 + wm*64 + i2*16 + quad*4 + r;    // slot row in [0,2560)
                int bb = mr / CAP;
                int cc = mr - bb*CAP;
                int sidx = (e*BB + bb)*CAP + cc;
                int tok = slot_token[sidx];
                if (tok < 0) continue;
                float g = slot_gate[sidx];
                float* orow = outp + ((size_t)bb*NN + tok)*DD + n0 + wn*64 + l16;
                #pragma unroll
                for (int j = 0; j < 4; j++)
                    atomicAdd(orow + j*16, g * (acc[i2][j][r] + bn[j]));
            }
        }
    }
}

// ---------------------------------------------------------------- loss
__global__ void MoE_loss(const float* __restrict__ proxy, const float* __restrict__ cnt,
                         float* __restrict__ out)
{
    int t = threadIdx.x;
    float v = proxy[t] * cnt[t];
    for (int off = 32; off; off >>= 1) v += __shfl_down(v, off, 64);
    if (t == 0) out[0] = v * (0.01f / ((float)NN * (float)NN));
}

// ================================================================ launch
extern "C" void kernel_launch(void* const* d_in, const int* in_sizes, int n_in,
                              void* d_out, int out_size, void* d_ws, size_t ws_size,
                              hipStream_t stream) {
    const float* x  = (const float*)d_in[0];
    const float* wg = (const float*)d_in[1];
    const float* w1 = (const float*)d_in[2];
    const float* b1 = (const float*)d_in[3];
    const float* w2 = (const float*)d_in[4];
    const float* b2 = (const float*)d_in[5];
    const float* rp = (const float*)d_in[6];
    float* out = (float*)d_out;

    char* w = (char*)d_ws;
    auto alloc = [&](size_t bytes) -> char* {
        char* p = w; w += (bytes + 255) & ~(size_t)255; return p;
    };
    u16*   w1b  = (u16*)alloc((size_t)2*EE*DD*HH);          // [E][H][D] bf16
    u16*   w2b  = (u16*)alloc((size_t)2*EE*HH*DD);          // [E][D][H] bf16
    u16*   Abuf = (u16*)alloc((size_t)2*EE*MBC*DD);         // [E][M][K]
    u16*   Hbuf = (u16*)alloc((size_t)2*EE*MBC*HH);         // [E][M][H]
    int*   i1   = (int*)alloc(4*NTOK);
    int*   i2   = (int*)alloc(4*NTOK);
    int*   keep = (int*)alloc(4*NTOK);
    float* g1   = (float*)alloc(4*NTOK);
    float* g2   = (float*)alloc(4*NTOK);
    int*   slot = (int*)alloc(4*EE*BB*CAP);
    float* sgate= (float*)alloc(4*EE*BB*CAP);
    float* stats = (float*)alloc(4*128);                    // proxy[64], cnt[64]
    float* proxy = stats;
    float* cnt   = stats + 64;

    MoE_zero_stats<<<1, 128, 0, stream>>>(stats);
    // w1: [E][1024][4096] -> [E][4096][1024]
    MoE_transpose_bf16<<<EE*16*64, 256, 0, stream>>>(w1, w1b, 1024, 4096, 16, 64);
    // w2: [E][4096][1024] -> [E][1024][4096]
    MoE_transpose_bf16<<<EE*64*16, 256, 0, stream>>>(w2, w2b, 4096, 1024, 64, 16);
    MoE_gating<<<NTOK/4, 256, 0, stream>>>(x, wg, rp, i1, i2, g1, g2, keep, proxy, cnt, out);
    MoE_scan<<<BB, 256, 0, stream>>>(i1, i2, keep, g1, g2, slot, sgate);
    MoE_dispatch<<<EE*BB*CAP/4, 256, 0, stream>>>(x, slot, Abuf);
    // GEMM1: [2560x1024] @ w1b -> gelu -> Hbuf (bf16)
    MoE_gemm_bt<0><<<EE*20*32, 256, 0, stream>>>(Abuf, w1b, Hbuf, b1, nullptr, nullptr, MBC, HH, DD, 20, 32);
    // GEMM2: [2560x4096] @ w2b -> fused gate-weighted atomic scatter into out
    MoE_gemm_bt<1><<<EE*20*8, 256, 0, stream>>>(Hbuf, w2b, out, b2, slot, sgate, MBC, DD, HH, 20, 8);
    MoE_loss<<<1, 64, 0, stream>>>(proxy, cnt, out + (size_t)NTOK*DD);
}